// Round 1
// 3429.340 us; speedup vs baseline: 1.2197x; 1.2197x over previous
//
#include <hip/hip_runtime.h>
#include <hip/hip_bf16.h>

// LSTM B=32,T=512,D=512,H=1024, persistent kernel.
// R5 changes vs R4:
//  - Tree barrier + leader-spin + broadcast REPLACED by 64-entry flag array:
//    producer stores flag[bid]=t+1 (plain agent store after vmcnt drain, no
//    RMW); every wave polls all 64 flags with ONE coalesced 64-lane atomic
//    load and releases itself via __all(flag >= t). 2 serialized RMW fabric
//    hops + syncthreads-E removed from the per-step critical path.
//  - K-split rebalanced: every wave = 4 h-kb + 2 x-kb (was 6 contiguous).
//    x MFMAs (h-independent) run BEFORE the poll -> fill the wait window;
//    dependent tail after release shrinks 6->4 k-iters.
//  - All 8 h fragments issued back-to-back after release, then unpack+MFMA
//    (one exposed latency instead of serialized atomic-load/MFMA chain).
//  - LDS h-stage moved to its own 2KB buffer (no zpart overlay) -> drop
//    sync B. 5 syncthreads/step -> 3.

#define B_   32
#define T_   512
#define D_   512
#define H_   1024
#define KTOT 1536
#define N4H  4096
#define NBLK 64

typedef __bf16 bf16_t;
typedef __bf16 bf16x8 __attribute__((ext_vector_type(8)));
typedef float f32x4 __attribute__((ext_vector_type(4)));

#define MFMA16(a, b, c) __builtin_amdgcn_mfma_f32_16x16x32_bf16(a, b, c, 0, 0, 0)

// ---------------------------------------------------------------------------
__global__ void wconv_kernel(const float* __restrict__ Wx,
                             const float* __restrict__ Wh,
                             bf16_t* __restrict__ Wt) {
    __shared__ float tile[32][33];
    int k0 = blockIdx.x * 32;
    int n0 = blockIdx.y * 32;
    int tx = threadIdx.x;
    int ty = threadIdx.y;
    for (int i = ty; i < 32; i += 8) {
        int k = k0 + i;
        float v = (k < H_) ? Wh[(size_t)k * N4H + n0 + tx]
                           : Wx[(size_t)(k - H_) * N4H + n0 + tx];
        tile[i][tx] = v;
    }
    __syncthreads();
    for (int i = ty; i < 32; i += 8)
        Wt[(size_t)(n0 + i) * KTOT + k0 + tx] = (bf16_t)tile[tx][i];
}

// ---------------------------------------------------------------------------
// X -> packed uint32 per element: low16 = bf16(hi), high16 = bf16(residual).
__global__ void xconv_kernel(const float4* __restrict__ X,
                             uint4* __restrict__ Xpk) {
    int i = blockIdx.x * blockDim.x + threadIdx.x;
    float4 v = X[i];
    float arr[4] = {v.x, v.y, v.z, v.w};
    unsigned pk[4];
#pragma unroll
    for (int j = 0; j < 4; ++j) {
        bf16_t h = (bf16_t)arr[j];
        bf16_t l = (bf16_t)(arr[j] - (float)h);
        pk[j] = (unsigned)__builtin_bit_cast(unsigned short, h) |
                ((unsigned)__builtin_bit_cast(unsigned short, l) << 16);
    }
    Xpk[i] = make_uint4(pk[0], pk[1], pk[2], pk[3]);
}

// ---------------------------------------------------------------------------
__device__ __forceinline__ void unpack16(const unsigned short* s,
                                         bf16x8* hi, bf16x8* lo) {
#pragma unroll
    for (int j = 0; j < 8; ++j) {
        (*hi)[j] = __builtin_bit_cast(bf16_t, s[2 * j]);
        (*lo)[j] = __builtin_bit_cast(bf16_t, s[2 * j + 1]);
    }
}

// x fragment: normal cacheable 2x dwordx4.
__device__ __forceinline__ void load_x_frag(const unsigned* p,
                                            bf16x8* hi, bf16x8* lo) {
    union { uint4 q[2]; unsigned short s[16]; } v;
    v.q[0] = *(const uint4*)p;
    v.q[1] = *(const uint4*)(p + 4);
    unpack16(v.s, hi, lo);
}

// ---------------------------------------------------------------------------
// Block b owns h-cols [16b,16b+16). Wave w: h-k in [128w,128w+128) (4 kb) +
// x-k in [1024+64w, 1024+64w+64) (2 kb), all 4 gates. hpk ping-pong,
// frag-major layout, accessed only via sc1 (agent-scope) atomics.
__global__ __launch_bounds__(512, 2) void lstm_kernel(
    const bf16_t* __restrict__ Wt,
    const unsigned* __restrict__ Xpk,
    unsigned* __restrict__ hpk,
    const float* __restrict__ bias,
    const int* __restrict__ seqlen,
    float* __restrict__ out,
    unsigned* __restrict__ flags) {
    __shared__ float zpart[8][4][32][16];  // 64 KB partial sums
    __shared__ unsigned stage[512];        // 2 KB h-store stage (disjoint)

    const int tid  = threadIdx.x;
    const int w    = tid >> 6;
    const int lane = tid & 63;
    const int quad = lane >> 4;
    const int lcol = lane & 15;
    const int hc0  = blockIdx.x * 16;
    const int HW_  = 32768;                // uints per h buffer (B_*H_)

    // Weight fragments: 4 gates x 6 k-iters (4 h + 2 x), loaded once.
    bf16x8 wreg[24];
#pragma unroll
    for (int g = 0; g < 4; ++g)
#pragma unroll
        for (int it = 0; it < 6; ++it) {
            int k = (it < 4) ? (w * 128 + it * 32)
                             : (1024 + w * 64 + (it - 4) * 32);
            wreg[g * 6 + it] = *(const bf16x8*)(
                Wt + (size_t)(g * H_ + hc0 + lcol) * KTOT + k + quad * 8);
        }

    // Epilogue mapping: 512 threads = one (batch,col) element each.
    const int eb = tid >> 4, ec = tid & 15;
    const int col = hc0 + ec;
    float creg = 0.f;
    const float b0 = bias[col];
    const float b1 = bias[H_ + col];
    const float b2 = bias[2 * H_ + col];
    const float b3 = bias[3 * H_ + col];
    const int slm1 = seqlen[eb] - 1;
    // LDS stage index (destination-ordered within this block's h region).
    const int stageIdx = (eb >> 4) * 256 + ((ec >> 3) * 16 + (eb & 15)) * 8 +
                         (ec & 7);
    // Store-phase constants.
    const int kbB  = (hc0 >> 5) * 1024;    // k-block base (uints)
    const int qlo  = (hc0 >> 4) & 1;       // which quad-pair within k-block
    const int dst0 = kbB + (tid >> 7) * 512 + qlo * 256 + (tid & 127) * 2;

#pragma unroll 1
    for (int t = 0; t < T_; ++t) {
        const unsigned* hr = hpk + (size_t)(t & 1) * HW_;
        unsigned*       hw = hpk + (size_t)((t + 1) & 1) * HW_;

        f32x4 acc[8];
#pragma unroll
        for (int i = 0; i < 8; ++i) acc[i] = (f32x4){0.f, 0.f, 0.f, 0.f};

        // ---- x part: independent of h(t-1), fills the wait window ----
#pragma unroll
        for (int it = 4; it < 6; ++it) {
            bf16x8 a0h, a0l, a1h, a1l;
            int kx = w * 64 + (it - 4) * 32 + quad * 8;
            load_x_frag(Xpk + ((size_t)lcol * T_ + t) * D_ + kx, &a0h, &a0l);
            load_x_frag(Xpk + ((size_t)(lcol + 16) * T_ + t) * D_ + kx,
                        &a1h, &a1l);
#pragma unroll
            for (int g = 0; g < 4; ++g) {
                bf16x8 wv = wreg[g * 6 + it];
                acc[g * 2]     = MFMA16(a0h, wv, acc[g * 2]);
                acc[g * 2]     = MFMA16(a0l, wv, acc[g * 2]);
                acc[g * 2 + 1] = MFMA16(a1h, wv, acc[g * 2 + 1]);
                acc[g * 2 + 1] = MFMA16(a1l, wv, acc[g * 2 + 1]);
            }
        }

        // ---- wait for h(t-1): per-wave poll of 64 producer flags ----
        // One coalesced 64-lane load per poll; no RMW, no broadcast sync.
        {
            const unsigned tgt = (unsigned)t;
            for (;;) {
                unsigned v = __hip_atomic_load(flags + lane, __ATOMIC_RELAXED,
                                               __HIP_MEMORY_SCOPE_AGENT);
                if (__all((int)(v >= tgt))) break;
                __builtin_amdgcn_s_sleep(1);
            }
            asm volatile("" ::: "memory");
        }

        // ---- h part: issue all 8 fragment loads, then unpack + MFMA ----
        union Raw { unsigned long long u[4]; unsigned short s[16]; };
        Raw r[8];
#pragma unroll
        for (int it = 0; it < 4; ++it) {
            const unsigned long long* q = (const unsigned long long*)(
                hr + (w * 4 + it) * 1024 + lane * 8);
#pragma unroll
            for (int j = 0; j < 4; ++j)
                r[it * 2].u[j] = __hip_atomic_load(
                    q + j, __ATOMIC_RELAXED, __HIP_MEMORY_SCOPE_AGENT);
#pragma unroll
            for (int j = 0; j < 4; ++j)
                r[it * 2 + 1].u[j] = __hip_atomic_load(
                    q + 256 + j, __ATOMIC_RELAXED, __HIP_MEMORY_SCOPE_AGENT);
        }
#pragma unroll
        for (int it = 0; it < 4; ++it) {
            bf16x8 a0h, a0l, a1h, a1l;
            unpack16(r[it * 2].s, &a0h, &a0l);
            unpack16(r[it * 2 + 1].s, &a1h, &a1l);
#pragma unroll
            for (int g = 0; g < 4; ++g) {
                bf16x8 wv = wreg[g * 6 + it];
                acc[g * 2]     = MFMA16(a0h, wv, acc[g * 2]);
                acc[g * 2]     = MFMA16(a0l, wv, acc[g * 2]);
                acc[g * 2 + 1] = MFMA16(a1h, wv, acc[g * 2 + 1]);
                acc[g * 2 + 1] = MFMA16(a1l, wv, acc[g * 2 + 1]);
            }
        }

#pragma unroll
        for (int g = 0; g < 4; ++g)
#pragma unroll
            for (int r4 = 0; r4 < 4; ++r4) {
                zpart[w][g][quad * 4 + r4][lcol]      = acc[g * 2][r4];
                zpart[w][g][16 + quad * 4 + r4][lcol] = acc[g * 2 + 1][r4];
            }
        __syncthreads();  // A: zpart complete

        // Epilogue (all 512 threads).
        float zi = b0, zf = b1, zg = b2, zo = b3;
#pragma unroll
        for (int ss = 0; ss < 8; ++ss) {
            zi += zpart[ss][0][eb][ec];
            zf += zpart[ss][1][eb][ec];
            zg += zpart[ss][2][eb][ec];
            zo += zpart[ss][3][eb][ec];
        }
        float ig = 1.f / (1.f + __expf(-zi));
        float fg = 1.f / (1.f + __expf(-zf));
        float og = 1.f / (1.f + __expf(-zo));
        float gg = 1.f - 2.f / (__expf(2.f * zg) + 1.f);
        creg = fg * creg + ig * gg;
        float hn = og * (1.f - 2.f / (__expf(2.f * creg) + 1.f));
        bf16_t hh = (bf16_t)hn;
        bf16_t hl = (bf16_t)(hn - (float)hh);
        unsigned pk = (unsigned)__builtin_bit_cast(unsigned short, hh) |
                      ((unsigned)__builtin_bit_cast(unsigned short, hl) << 16);
        stage[stageIdx] = pk;  // disjoint LDS region: no sync needed before
        if (slm1 == t) out[eb * H_ + col] = hn;

        __syncthreads();  // C: stage complete (and all zpart reads done)

        if (tid < 256) {
            unsigned long long val = ((const unsigned long long*)stage)[tid];
            __hip_atomic_store((unsigned long long*)(hw + dst0), val,
                               __ATOMIC_RELAXED, __HIP_MEMORY_SCOPE_AGENT);
        }
        // Drain h stores (waves 0-3), then signal readiness with ONE plain
        // agent store. No RMW, no tree, no release barrier.
        asm volatile("s_waitcnt vmcnt(0)" ::: "memory");
        __syncthreads();  // D: all stores drained, stage reads done
        if (tid == 0)
            __hip_atomic_store(flags + blockIdx.x, (unsigned)(t + 1),
                               __ATOMIC_RELAXED, __HIP_MEMORY_SCOPE_AGENT);
    }
}

// ---------------------------------------------------------------------------
extern "C" void kernel_launch(void* const* d_in, const int* in_sizes, int n_in,
                              void* d_out, int out_size, void* d_ws, size_t ws_size,
                              hipStream_t stream) {
    const float* inputs = (const float*)d_in[0];
    const int*   seqlen = (const int*)d_in[1];
    const float* Wx     = (const float*)d_in[2];
    const float* Wh     = (const float*)d_in[3];
    const float* bias   = (const float*)d_in[4];
    float* out = (float*)d_out;

    char* ws = (char*)d_ws;
    size_t o = 0;
    bf16_t*   Wt    = (bf16_t*)(ws + o);   o += (size_t)N4H * KTOT * 2;   // 12.6MB
    unsigned* Xpk   = (unsigned*)(ws + o); o += (size_t)B_ * T_ * D_ * 4; // 33.6MB
    unsigned* hpk   = (unsigned*)(ws + o); o += (size_t)2 * B_ * H_ * 4;  // 256KB
    unsigned* flags = (unsigned*)(ws + o); o += 4096;

    wconv_kernel<<<dim3(48, 128), dim3(32, 8), 0, stream>>>(Wx, Wh, Wt);
    xconv_kernel<<<(B_ * T_ * D_ / 4) / 256, 256, 0, stream>>>(
        (const float4*)inputs, (uint4*)Xpk);
    hipMemsetAsync(hpk, 0, (size_t)B_ * H_ * 4, stream);  // ping p=0 zeros
    hipMemsetAsync(flags, 0, 4096, stream);               // readiness flags

    lstm_kernel<<<NBLK, 512, 0, stream>>>(Wt, Xpk, hpk, bias, seqlen, out, flags);
}